// Round 2
// 336.414 us; speedup vs baseline: 1.0236x; 1.0236x over previous
//
#include <hip/hip_runtime.h>
#include <math.h>

// SSIM loss, fused single pass.
// R6 = R5 with macro-hygiene fix (locals t1/t2 collided with STEP params).
// R5: (1) 4-channel algebraic reduction: blur (u,v,u^2,v^2) with u=x+y, v=x-y
//     instead of (x,y,x^2,y^2,xy). SSIM only needs mxx+myy, never mxx/myy
//     separately: 4mxmy=MU^2-MV^2, 2(mx^2+my^2)=MU^2+MV^2, 4mxy=MUU-MVV,
//     2(mxx+myy)=MUU+MVV. h-blur 7->6 VALU/tap, v-blur 55->44 fma,
//     ring 55->44 named regs, LDS traffic unchanged.
// (2) NCHUNKY 2->3: 1488 blocks = 5.8/CU (LDS 24KB permits 6) to lift
//     occupancy from ~31% and hide ds_read latency / barrier drain.
// R4 lesson kept: ring buffers as NAMED scalars (macro-unrolled ring phases)
// so they are SSA by construction -> guaranteed VGPRs.

#define KS    11
#define IMG_H 256
#define IMG_W 256
#define PADW  268          // tap reads up to col 265, no guard needed
#define OUTD  246
#define NIMG  496
#define OUT_ROWS 82        // 3 y-chunks x 82 = 246
#define NCHUNKY  3
#define NCHUNKS  9         // ceil((82+10)/11)
#define C1F   0.0001f
#define C2F   0.0009f

// 11-tap gaussian (sigma=1.5), normalized; computed in double offline.
__device__ constexpr float GW[KS] = {
    0.00102838f, 0.00759876f, 0.03600077f, 0.10936068f, 0.21300554f,
    0.26601173f,
    0.21300554f, 0.10936068f, 0.03600077f, 0.00759876f, 0.00102838f
};

// horizontal blur of row K of the staged tile, result -> ring slot C
// channels: u, v, u^2, v^2  (squares reuse wu/wv: 6 VALU per tap)
#define HBLUR_STORE(K, C)                                                  \
  do {                                                                     \
    float hu = 0.f, hv = 0.f, huu = 0.f, hvv = 0.f;                        \
    _Pragma("unroll")                                                      \
    for (int t = 0; t < KS; ++t) {                                         \
      const float2 val = rowbuf[K][tid + t];                               \
      const float w  = GW[t];                                              \
      const float wu = w * val.x, wv = w * val.y;                          \
      hu  += wu;          hv  += wv;                                       \
      huu += wu * val.x;  hvv += wv * val.y;                               \
    }                                                                      \
    su##C = hu; sv##C = hv; suu##C = huu; svv##C = hvv;                    \
  } while (0)

#define VDOT(M, t0,t1,t2,t3,t4,t5,t6,t7,t8,t9,t10)                         \
  (GW[0]*M##t0 + GW[1]*M##t1 + GW[2]*M##t2 + GW[3]*M##t3 + GW[4]*M##t4     \
 + GW[5]*M##t5 + GW[6]*M##t6 + GW[7]*M##t7 + GW[8]*M##t8 + GW[9]*M##t9     \
 + GW[10]*M##t10)

// one ring phase: h-blur row jj+K into slot K (== t10), then if a full 11-row
// window is resident, v-blur (taps read slots (K+1+t)%11 = t0..t10) + SSIM.
// Reconstruction:
//   A=MU^2, B=MV^2:  2*mx*my = (A-B)/2,  mx^2+my^2 = (A+B)/2
//   2*m(xy) = (MUU-MVV)/2,  m(xx)+m(yy) = (MUU+MVV)/2
#define STEP(K, t0,t1,t2,t3,t4,t5,t6,t7,t8,t9,t10)                         \
  HBLUR_STORE(K, t10);                                                     \
  {                                                                        \
    const int jrow = jj + K;                                               \
    const int irow = jrow - (KS - 1);                                      \
    if (jrow >= KS - 1 && irow < OUT_ROWS) {   /* wave-uniform */          \
      const float MU  = VDOT(su,  t0,t1,t2,t3,t4,t5,t6,t7,t8,t9,t10);     \
      const float MV  = VDOT(sv,  t0,t1,t2,t3,t4,t5,t6,t7,t8,t9,t10);     \
      const float MUU = VDOT(suu, t0,t1,t2,t3,t4,t5,t6,t7,t8,t9,t10);     \
      const float MVV = VDOT(svv, t0,t1,t2,t3,t4,t5,t6,t7,t8,t9,t10);     \
      const float A   = MU * MU;                                           \
      const float B   = MV * MV;                                           \
      const float dAB = A - B;            /* = 4 mx my          */         \
      const float sAB = A + B;            /* = 2(mx^2+my^2)     */         \
      const float dM  = MUU - MVV;        /* = 4 m(xy)          */         \
      const float sM  = MUU + MVV;        /* = 2(m(xx)+m(yy))   */         \
      const float n1 = 0.5f * dAB + C1F;        /* 2 mx my + C1 */         \
      const float d1 = 0.5f * sAB + C1F;        /* mx^2+my^2+C1 */         \
      const float n2 = 0.5f * (dM - dAB) + C2F; /* 2 cov   + C2 */         \
      const float d2 = 0.5f * (sM - sAB) + C2F; /* vx + vy + C2 */         \
      const float num = n1 * n2;                                           \
      const float den = d1 * d2;                                           \
      ssum += active ? num * __builtin_amdgcn_rcpf(den) : 0.f;             \
    }                                                                      \
  }

__global__ __launch_bounds__(256, 4)
void ssim_fused_kernel(const float* __restrict__ X, const float* __restrict__ Y,
                       double* __restrict__ accum) {
    __shared__ float2 rowbuf[KS][PADW];
    __shared__ float  wsum[4];

    const int img    = blockIdx.x;
    const int out_r0 = blockIdx.y * OUT_ROWS;
    const int tid    = threadIdx.x;
    const bool active = (tid < OUTD);

    const float* Xi = X + (size_t)img * (IMG_H * IMG_W);
    const float* Yi = Y + (size_t)img * (IMG_H * IMG_W);

    // 44 named ring registers (slot = local_row % 11)
    float su0=0,su1=0,su2=0,su3=0,su4=0,su5=0,su6=0,su7=0,su8=0,su9=0,su10=0;
    float sv0=0,sv1=0,sv2=0,sv3=0,sv4=0,sv5=0,sv6=0,sv7=0,sv8=0,sv9=0,sv10=0;
    float suu0=0,suu1=0,suu2=0,suu3=0,suu4=0,suu5=0,suu6=0,suu7=0,suu8=0,suu9=0,suu10=0;
    float svv0=0,svv1=0,svv2=0,svv3=0,svv4=0,svv5=0,svv6=0,svv7=0,svv8=0,svv9=0,svv10=0;

    float ssum = 0.0f;

    for (int c = 0; c < NCHUNKS; ++c) {
        const int jj = c * KS;
        __syncthreads();
        #pragma unroll
        for (int r = 0; r < KS; ++r) {
            int row = out_r0 + jj + r;
            row = min(row, IMG_H - 1);   // clamped rows feed discarded outputs
            const float xv = Xi[(row << 8) + tid];
            const float yv = Yi[(row << 8) + tid];
            rowbuf[r][tid] = make_float2(xv + yv, xv - yv);
        }
        __syncthreads();

        STEP(0,  1,2,3,4,5,6,7,8,9,10,0)
        STEP(1,  2,3,4,5,6,7,8,9,10,0,1)
        STEP(2,  3,4,5,6,7,8,9,10,0,1,2)
        STEP(3,  4,5,6,7,8,9,10,0,1,2,3)
        STEP(4,  5,6,7,8,9,10,0,1,2,3,4)
        STEP(5,  6,7,8,9,10,0,1,2,3,4,5)
        STEP(6,  7,8,9,10,0,1,2,3,4,5,6)
        STEP(7,  8,9,10,0,1,2,3,4,5,6,7)
        STEP(8,  9,10,0,1,2,3,4,5,6,7,8)
        STEP(9,  10,0,1,2,3,4,5,6,7,8,9)
        STEP(10, 0,1,2,3,4,5,6,7,8,9,10)
    }

    // block reduction
    #pragma unroll
    for (int off = 32; off > 0; off >>= 1)
        ssum += __shfl_down(ssum, off);
    const int lane = tid & 63, wid = tid >> 6;
    if (lane == 0) wsum[wid] = ssum;
    __syncthreads();
    if (tid == 0) {
        const double s = (double)wsum[0] + (double)wsum[1]
                       + (double)wsum[2] + (double)wsum[3];
        atomicAdd(accum, s);
    }
}

__global__ void ssim_finalize_kernel(const double* __restrict__ accum,
                                     float* __restrict__ out) {
    const double cnt = (double)NIMG * OUTD * OUTD;   // 30,015,936
    out[0] = (float)(1.0 - accum[0] / cnt);
}

extern "C" void kernel_launch(void* const* d_in, const int* in_sizes, int n_in,
                              void* d_out, int out_size, void* d_ws, size_t ws_size,
                              hipStream_t stream) {
    (void)in_sizes; (void)n_in; (void)out_size; (void)ws_size;
    const float* X = (const float*)d_in[0];
    const float* Y = (const float*)d_in[1];
    float* out = (float*)d_out;
    double* acc = (double*)d_ws;

    hipMemsetAsync(d_ws, 0, sizeof(double), stream);

    dim3 grid(NIMG, NCHUNKY);
    hipLaunchKernelGGL(ssim_fused_kernel, grid, dim3(256), 0, stream, X, Y, acc);
    hipLaunchKernelGGL(ssim_finalize_kernel, dim3(1), dim3(1), 0, stream, acc, out);
}